// Round 9
// baseline (69.695 us; speedup 1.0000x reference)
//
#include <hip/hip_runtime.h>
#include <hip/hip_bf16.h>

#define NROWS 8192
#define DCOLS 256
#define NTILES 2080   // 64*65/2 upper-triangle 128x128 tiles
constexpr float EPSV = 1e-6f;

typedef __attribute__((ext_vector_type(8))) short short8;
typedef __attribute__((ext_vector_type(4))) float f32x4;

// ---------------- K12: row norms + per-block colsum partials (no atomics) ----------------
__global__ void k12_fused(const float* __restrict__ in, float* __restrict__ inv,
                          float* __restrict__ part) {
    int t = threadIdx.x, lane = t & 63, wave = t >> 6;
    int r0 = blockIdx.x * 32;
    __shared__ float cs[4][256];
    float4 acc4 = {0.f, 0.f, 0.f, 0.f};
    #pragma unroll
    for (int rr = 0; rr < 8; ++rr) {
        int row = r0 + wave * 8 + rr;
        float4 v = *reinterpret_cast<const float4*>(&in[row * DCOLS + lane * 4]);
        float s = v.x * v.x + v.y * v.y + v.z * v.z + v.w * v.w;
        #pragma unroll
        for (int o = 1; o < 64; o <<= 1) s += __shfl_xor(s, o);
        float iv = 1.0f / (sqrtf(s) + EPSV);
        if (lane == 0) inv[row] = iv;
        acc4.x += v.x * iv; acc4.y += v.y * iv; acc4.z += v.z * iv; acc4.w += v.w * iv;
    }
    *reinterpret_cast<float4*>(&cs[wave][lane * 4]) = acc4;
    __syncthreads();
    part[blockIdx.x * 256 + t] = cs[0][t] + cs[1][t] + cs[2][t] + cs[3][t];
}

// ---------------- K3: reduce partials -> colmean; center; write FRAGMENT-PACKED bf16 ----------------
// Packed layout: byte(row,k) = (row>>4)*8192 + (k>>5)*1024 + ((row&15) + (((k>>3)&3)<<4))*16 + (k&7)*2
// so that a 16x16x32 MFMA fragment (16-row block rb, k-slice kk) is the contiguous 1KB
// [rb*8192 + kk*1024 .. +1024), lane l owning bytes l*16..l*16+15.
__global__ void k3_center(const float* __restrict__ in, const float* __restrict__ inv,
                          const float* __restrict__ part,
                          __hip_bfloat16* __restrict__ cbf2, float* __restrict__ sqn) {
    int t = threadIdx.x, lane = t & 63, wave = t >> 6;
    int r0 = blockIdx.x * 32;
    __shared__ float cm[256];
    float m = 0.f;
    #pragma unroll 8
    for (int b = 0; b < 256; ++b) m += part[b * 256 + t];
    cm[t] = m * (1.0f / NROWS);
    __syncthreads();
    float4 m4 = *reinterpret_cast<const float4*>(&cm[lane * 4]);
    // this thread's 4 cols k0..k0+3 land at a fixed packed sub-offset:
    int k0 = lane * 4;
    int kk = k0 >> 5, c8 = (k0 >> 3) & 3, j8 = k0 & 7;
    #pragma unroll
    for (int rr = 0; rr < 8; ++rr) {
        int row = r0 + wave * 8 + rr;
        float iv = inv[row];
        float4 v = *reinterpret_cast<const float4*>(&in[row * DCOLS + k0]);
        float4 cv = {v.x * iv - m4.x, v.y * iv - m4.y, v.z * iv - m4.z, v.w * iv - m4.w};
        __hip_bfloat16 hb[4] = {__float2bfloat16(cv.x), __float2bfloat16(cv.y),
                                __float2bfloat16(cv.z), __float2bfloat16(cv.w)};
        size_t boff = (size_t)(row >> 4) * 8192 + (size_t)kk * 1024
                    + (size_t)(((row & 15) + (c8 << 4)) << 4) + (size_t)(j8 << 1);
        *reinterpret_cast<ushort4*>(reinterpret_cast<char*>(cbf2) + boff) =
            *reinterpret_cast<ushort4*>(hb);
        float s = cv.x * cv.x + cv.y * cv.y + cv.z * cv.z + cv.w * cv.w;
        #pragma unroll
        for (int o = 1; o < 64; o <<= 1) s += __shfl_xor(s, o);
        if (lane == 0) sqn[row] = s;
    }
}

// ---------------- K4: 128x128 tile, 4 waves (each 64x64), NO LDS / NO barriers ----------------
// Fragments loaded directly from the L2-resident packed cbf2: one coalesced
// global_load_dwordx4 (1KB contiguous per wave) per fragment. 8 kk-steps of
// {8 loads + 16 MFMA}; compiler pipelines loads across steps.
__global__ __launch_bounds__(256, 3) void k4_dist(const __hip_bfloat16* __restrict__ cbf2,
                                                  const float* __restrict__ sqn,
                                                  float* __restrict__ partial) {
    __shared__ float red4[4];

    int bid = blockIdx.x;
    int idx = (bid & 7) * (NTILES / 8) + (bid >> 3);   // XCD swizzle, 2080%8==0
    int q = (int)((sqrtf(8.0f * (float)idx + 1.0f) - 1.0f) * 0.5f);
    while ((q + 1) * (q + 2) / 2 <= idx) ++q;
    while (q * (q + 1) / 2 > idx) --q;
    int p = idx - q * (q + 1) / 2;

    int brow = p * 128, bcol = q * 128;
    int t = threadIdx.x, lane = t & 63, wave = t >> 6;
    int wr = wave >> 1, wc = wave & 1;   // 2x2 wave grid, 64x64 each

    const char* lbase = (const char*)cbf2 + lane * 16;
    const char* Ab = lbase + (size_t)(p * 8 + wr * 4) * 8192;
    const char* Bb = lbase + (size_t)(q * 8 + wc * 4) * 8192;

    f32x4 acc[4][4] = {};

    #pragma unroll
    for (int kk = 0; kk < 8; ++kk) {
        short8 af[4], bf[4];
        #pragma unroll
        for (int m = 0; m < 4; ++m)
            af[m] = *reinterpret_cast<const short8*>(Ab + m * 8192 + kk * 1024);
        #pragma unroll
        for (int n = 0; n < 4; ++n)
            bf[n] = *reinterpret_cast<const short8*>(Bb + n * 8192 + kk * 1024);
        #pragma unroll
        for (int m = 0; m < 4; ++m)
            #pragma unroll
            for (int n = 0; n < 4; ++n)
                acc[m][n] = __builtin_amdgcn_mfma_f32_16x16x32_bf16(af[m], bf[n], acc[m][n], 0, 0, 0);
    }

    // epilogue: sq_dist = sqn_i + sqn_j - 2*gram; accumulate sqrt
    float local = 0.0f;
    int r4v = (lane >> 4) * 4;
    int cn = lane & 15;
    #pragma unroll
    for (int n = 0; n < 4; ++n) {
        float sj = sqn[bcol + wc * 64 + n * 16 + cn];
        #pragma unroll
        for (int m = 0; m < 4; ++m) {
            int i0 = brow + wr * 64 + m * 16 + r4v;
            #pragma unroll
            for (int r = 0; r < 4; ++r) {
                float sq = sqn[i0 + r] + sj - 2.0f * acc[m][n][r];
                local += (sq > 0.0f) ? sqrtf(sq) : 0.0f;
            }
        }
    }
    #pragma unroll
    for (int o = 1; o < 64; o <<= 1) local += __shfl_xor(local, o);
    if (lane == 0) red4[wave] = local;
    __syncthreads();
    if (t == 0) {
        float w = (p == q) ? 1.0f : 2.0f;
        partial[idx] = w * (red4[0] + red4[1] + red4[2] + red4[3]);
    }
}

// ---------------- K5: final scalar ----------------
__global__ void k5_final(const float* __restrict__ sqn, const float* __restrict__ partial,
                         float* __restrict__ out) {
    int t = threadIdx.x;
    int lane = t & 63, wave = t >> 6;
    float s = 0.0f;
    for (int r = t; r < NROWS; r += 1024) s += sqn[r];
    double ds = 0.0;
    for (int r = t; r < NTILES; r += 1024) ds += (double)partial[r];
    #pragma unroll
    for (int o = 1; o < 64; o <<= 1) { s += __shfl_xor(s, o); ds += __shfl_xor(ds, o); }
    __shared__ float redf[16];
    __shared__ double redd[16];
    if (lane == 0) { redf[wave] = s; redd[wave] = ds; }
    __syncthreads();
    if (t == 0) {
        float sumsq = 0.f; double sd = 0.0;
        #pragma unroll
        for (int i = 0; i < 16; ++i) { sumsq += redf[i]; sd += redd[i]; }
        double md = sd / ((double)NROWS * (double)NROWS);
        out[0] = (float)DCOLS / sumsq + (float)log(md);
    }
}

extern "C" void kernel_launch(void* const* d_in, const int* in_sizes, int n_in,
                              void* d_out, int out_size, void* d_ws, size_t ws_size,
                              hipStream_t stream) {
    const float* emb = (const float*)d_in[0];
    float* out = (float*)d_out;
    char* ws = (char*)d_ws;

    float*  inv     = (float*)ws;                    // 8192 f32
    float*  sqn     = (float*)(ws + 36864);          // 8192 f32
    float*  partial = (float*)(ws + 69632);          // 2080 f32
    float*  part    = (float*)(ws + 81920);          // 256*256 f32 = 256KB
    __hip_bfloat16* cbf2 = (__hip_bfloat16*)(ws + 81920 + 262144); // 4 MB packed

    k12_fused <<<NROWS / 32, 256, 0, stream>>>(emb, inv, part);
    k3_center <<<NROWS / 32, 256, 0, stream>>>(emb, inv, part, cbf2, sqn);
    k4_dist   <<<NTILES, 256, 0, stream>>>(cbf2, sqn, partial);
    k5_final  <<<1, 1024, 0, stream>>>(sqn, partial, out);
}

// Round 10
// 67.358 us; speedup vs baseline: 1.0347x; 1.0347x over previous
//
#include <hip/hip_runtime.h>
#include <hip/hip_bf16.h>

#define NROWS 8192
#define DCOLS 256
#define NBLK 1056    // sum_{P2=0}^{31} (64-2*P2): 256x128 tile-pair blocks
constexpr float EPSV = 1e-6f;

typedef __attribute__((ext_vector_type(8))) short short8;
typedef __attribute__((ext_vector_type(16))) float f32x16;

__device__ __forceinline__ void async16(void* lds, const void* g) {
    __builtin_amdgcn_global_load_lds(
        (const __attribute__((address_space(1))) void*)g,
        (__attribute__((address_space(3))) void*)lds, 16, 0, 0);
}

// ---------------- K12: row norms + per-block colsum partials (no atomics) ----------------
__global__ void k12_fused(const float* __restrict__ in, float* __restrict__ inv,
                          float* __restrict__ part) {
    int t = threadIdx.x, lane = t & 63, wave = t >> 6;
    int r0 = blockIdx.x * 32;
    __shared__ float cs[4][256];
    float4 acc4 = {0.f, 0.f, 0.f, 0.f};
    #pragma unroll
    for (int rr = 0; rr < 8; ++rr) {
        int row = r0 + wave * 8 + rr;
        float4 v = *reinterpret_cast<const float4*>(&in[row * DCOLS + lane * 4]);
        float s = v.x * v.x + v.y * v.y + v.z * v.z + v.w * v.w;
        #pragma unroll
        for (int o = 1; o < 64; o <<= 1) s += __shfl_xor(s, o);
        float iv = 1.0f / (sqrtf(s) + EPSV);
        if (lane == 0) inv[row] = iv;
        acc4.x += v.x * iv; acc4.y += v.y * iv; acc4.z += v.z * iv; acc4.w += v.w * iv;
    }
    *reinterpret_cast<float4*>(&cs[wave][lane * 4]) = acc4;
    __syncthreads();
    part[blockIdx.x * 256 + t] = cs[0][t] + cs[1][t] + cs[2][t] + cs[3][t];
}

// ---------------- K3: reduce partials -> colmean; center; row-major bf16 c; sq_norms ----------------
__global__ void k3_center(const float* __restrict__ in, const float* __restrict__ inv,
                          const float* __restrict__ part,
                          __hip_bfloat16* __restrict__ cbf, float* __restrict__ sqn) {
    int t = threadIdx.x, lane = t & 63, wave = t >> 6;
    int r0 = blockIdx.x * 32;
    __shared__ float cm[256];
    float m = 0.f;
    #pragma unroll 8
    for (int b = 0; b < 256; ++b) m += part[b * 256 + t];
    cm[t] = m * (1.0f / NROWS);
    __syncthreads();
    float4 m4 = *reinterpret_cast<const float4*>(&cm[lane * 4]);
    #pragma unroll
    for (int rr = 0; rr < 8; ++rr) {
        int row = r0 + wave * 8 + rr;
        float iv = inv[row];
        float4 v = *reinterpret_cast<const float4*>(&in[row * DCOLS + lane * 4]);
        float4 cv = {v.x * iv - m4.x, v.y * iv - m4.y, v.z * iv - m4.z, v.w * iv - m4.w};
        __hip_bfloat16 hb[4] = {__float2bfloat16(cv.x), __float2bfloat16(cv.y),
                                __float2bfloat16(cv.z), __float2bfloat16(cv.w)};
        *reinterpret_cast<ushort4*>(&cbf[row * DCOLS + lane * 4]) = *reinterpret_cast<ushort4*>(hb);
        float s = cv.x * cv.x + cv.y * cv.y + cv.z * cv.z + cv.w * cv.w;
        #pragma unroll
        for (int o = 1; o < 64; o <<= 1) s += __shfl_xor(s, o);
        if (lane == 0) sqn[row] = s;
    }
}

// ---------------- K4: 256x128 tile-pair, 8 waves (64x64 each, 32x32x16 MFMA) ----------------
// Block covers A-tiles p=2*P2, 2*P2+1 against B-tile q (shared B panel).
// Single-buffer BK=64 LDS (A 32KB + B 16KB), global_load_lds with swizzled source.
// Lower-triangle half gets weight 0; diag half weight 1; else 2.
__global__ __launch_bounds__(512, 4) void k4_dist(const __hip_bfloat16* __restrict__ cbf,
                                                  const float* __restrict__ sqn,
                                                  float* __restrict__ partial) {
    __shared__ ushort As[256 * 64];   // 32KB
    __shared__ ushort Bs[128 * 64];   // 16KB
    __shared__ float sqA[256], sqB[128];
    __shared__ float red8[8];

    int bid = blockIdx.x;
    int idx = (bid & 7) * (NBLK / 8) + (bid >> 3);   // XCD swizzle, 1056%8==0
    // decode: idx = P2*(65-P2) + (q - 2*P2), q in [2*P2, 64)
    int P2 = (int)((65.0f - sqrtf(65.0f * 65.0f - 4.0f * (float)idx)) * 0.5f);
    while (P2 > 0 && P2 * (65 - P2) > idx) --P2;
    while ((P2 + 1) * (65 - (P2 + 1)) <= idx) ++P2;
    int q = 2 * P2 + (idx - P2 * (65 - P2));

    int brow = P2 * 256, bcol = q * 128;
    int t = threadIdx.x, lane = t & 63, wave = t >> 6;
    int wr = wave >> 1, wc = wave & 1;   // 4x2 wave grid, each 64x64

    // staging source: lane l covers LDS row R+(l>>3), 16B chunk ((l&7)^(l>>3)); row&7==l>>3
    int laneOff = ((lane >> 3) * 512) + ((((lane & 7) ^ (lane >> 3)) & 7) << 4);
    const char* Ab = (const char*)cbf + (size_t)brow * 512 + laneOff;
    const char* Bb = (const char*)cbf + (size_t)bcol * 512 + laneOff;
    int Ra = wave * 32;   // A staging rows Ra..Ra+31 (4 groups)
    int Rb = wave * 16;   // B staging rows Rb..Rb+15 (2 groups)

    // stage sqn slices
    if (t < 256) sqA[t] = sqn[brow + t];
    else if (t < 384) sqB[t - 256] = sqn[bcol + t - 256];

    f32x16 acc[2][2] = {};

    #pragma unroll
    for (int s = 0; s < 4; ++s) {
        if (s) __syncthreads();          // all reads of previous slice done
        int kb = s * 128;
        async16(&As[Ra * 64],        Ab + (size_t)Ra * 512 + kb);
        async16(&As[(Ra + 8) * 64],  Ab + (size_t)(Ra + 8) * 512 + kb);
        async16(&As[(Ra + 16) * 64], Ab + (size_t)(Ra + 16) * 512 + kb);
        async16(&As[(Ra + 24) * 64], Ab + (size_t)(Ra + 24) * 512 + kb);
        async16(&Bs[Rb * 64],        Bb + (size_t)Rb * 512 + kb);
        async16(&Bs[(Rb + 8) * 64],  Bb + (size_t)(Rb + 8) * 512 + kb);
        __syncthreads();                 // vmcnt(0) drain: slice staged
        #pragma unroll
        for (int kk = 0; kk < 4; ++kk) {
            int colb = kk * 32 + ((lane >> 5) << 4);
            short8 af[2], bf[2];
            #pragma unroll
            for (int tm = 0; tm < 2; ++tm) {
                int row = wr * 64 + tm * 32 + (lane & 31);
                int off = (row * 128 + colb) ^ ((row & 7) << 4);
                af[tm] = *reinterpret_cast<const short8*>(reinterpret_cast<const char*>(As) + off);
            }
            #pragma unroll
            for (int tn = 0; tn < 2; ++tn) {
                int row = wc * 64 + tn * 32 + (lane & 31);
                int off = (row * 128 + colb) ^ ((row & 7) << 4);
                bf[tn] = *reinterpret_cast<const short8*>(reinterpret_cast<const char*>(Bs) + off);
            }
            #pragma unroll
            for (int tm = 0; tm < 2; ++tm)
                #pragma unroll
                for (int tn = 0; tn < 2; ++tn)
                    acc[tm][tn] = __builtin_amdgcn_mfma_f32_32x32x16_bf16(af[tm], bf[tn], acc[tm][tn], 0, 0, 0);
        }
    }

    // epilogue: per-wave weight (tile half h = wr>>1)
    int ptile = 2 * P2 + (wr >> 1);
    float wfac = (ptile < q) ? 2.0f : ((ptile == q) ? 1.0f : 0.0f);
    float local = 0.0f;
    if (wfac != 0.0f) {
        int cn = lane & 31;
        int rbase = (lane >> 5) * 4;
        #pragma unroll
        for (int tn = 0; tn < 2; ++tn) {
            float sj = sqB[wc * 64 + tn * 32 + cn];
            #pragma unroll
            for (int tm = 0; tm < 2; ++tm) {
                int i0 = wr * 64 + tm * 32 + rbase;
                #pragma unroll
                for (int reg = 0; reg < 16; ++reg) {
                    int irow = i0 + (reg & 3) + 8 * (reg >> 2);
                    float sq = sqA[irow] + sj - 2.0f * acc[tm][tn][reg];
                    local += (sq > 0.0f) ? sqrtf(sq) : 0.0f;
                }
            }
        }
        local *= wfac;
    }
    #pragma unroll
    for (int o = 1; o < 64; o <<= 1) local += __shfl_xor(local, o);
    if (lane == 0) red8[wave] = local;
    __syncthreads();
    if (t == 0) {
        float s8 = 0.f;
        #pragma unroll
        for (int i = 0; i < 8; ++i) s8 += red8[i];
        partial[idx] = s8;
    }
}

// ---------------- K5: final scalar ----------------
__global__ void k5_final(const float* __restrict__ sqn, const float* __restrict__ partial,
                         float* __restrict__ out) {
    int t = threadIdx.x;
    int lane = t & 63, wave = t >> 6;
    float s = 0.0f;
    for (int r = t; r < NROWS; r += 1024) s += sqn[r];
    double ds = 0.0;
    for (int r = t; r < NBLK; r += 1024) ds += (double)partial[r];
    #pragma unroll
    for (int o = 1; o < 64; o <<= 1) { s += __shfl_xor(s, o); ds += __shfl_xor(ds, o); }
    __shared__ float redf[16];
    __shared__ double redd[16];
    if (lane == 0) { redf[wave] = s; redd[wave] = ds; }
    __syncthreads();
    if (t == 0) {
        float sumsq = 0.f; double sd = 0.0;
        #pragma unroll
        for (int i = 0; i < 16; ++i) { sumsq += redf[i]; sd += redd[i]; }
        double md = sd / ((double)NROWS * (double)NROWS);
        out[0] = (float)DCOLS / sumsq + (float)log(md);
    }
}

extern "C" void kernel_launch(void* const* d_in, const int* in_sizes, int n_in,
                              void* d_out, int out_size, void* d_ws, size_t ws_size,
                              hipStream_t stream) {
    const float* emb = (const float*)d_in[0];
    float* out = (float*)d_out;
    char* ws = (char*)d_ws;

    float*  inv     = (float*)ws;                    // 8192 f32
    float*  sqn     = (float*)(ws + 36864);          // 8192 f32
    float*  partial = (float*)(ws + 69632);          // 1056 f32
    float*  part    = (float*)(ws + 81920);          // 256*256 f32 = 256KB
    __hip_bfloat16* cbf = (__hip_bfloat16*)(ws + 81920 + 262144); // 4 MB row-major

    k12_fused <<<NROWS / 32, 256, 0, stream>>>(emb, inv, part);
    k3_center <<<NROWS / 32, 256, 0, stream>>>(emb, inv, part, cbf, sqn);
    k4_dist   <<<NBLK, 512, 0, stream>>>(cbf, sqn, partial);
    k5_final  <<<1, 1024, 0, stream>>>(sqn, partial, out);
}

// Round 11
// 60.198 us; speedup vs baseline: 1.1578x; 1.1189x over previous
//
#include <hip/hip_runtime.h>
#include <hip/hip_bf16.h>

#define NROWS 8192
#define DCOLS 256
#define NTILES 2080   // 64*65/2 upper-triangle 128x128 tiles
constexpr float EPSV = 1e-6f;
constexpr float FP8_SCALE = 16.0f;          // c stored as fp8(16*c)
constexpr float GRAM_FIX = 2.0f / (FP8_SCALE * FP8_SCALE);  // 2*gram = GRAM_FIX*acc

typedef __attribute__((ext_vector_type(4))) float f32x4;

__device__ __forceinline__ void async16(void* lds, const void* g) {
    __builtin_amdgcn_global_load_lds(
        (const __attribute__((address_space(1))) void*)g,
        (__attribute__((address_space(3))) void*)lds, 16, 0, 0);
}

// ---------------- K12: row norms + per-block colsum partials (no atomics) ----------------
__global__ void k12_fused(const float* __restrict__ in, float* __restrict__ inv,
                          float* __restrict__ part) {
    int t = threadIdx.x, lane = t & 63, wave = t >> 6;
    int r0 = blockIdx.x * 32;
    __shared__ float cs[4][256];
    float4 acc4 = {0.f, 0.f, 0.f, 0.f};
    #pragma unroll
    for (int rr = 0; rr < 8; ++rr) {
        int row = r0 + wave * 8 + rr;
        float4 v = *reinterpret_cast<const float4*>(&in[row * DCOLS + lane * 4]);
        float s = v.x * v.x + v.y * v.y + v.z * v.z + v.w * v.w;
        #pragma unroll
        for (int o = 1; o < 64; o <<= 1) s += __shfl_xor(s, o);
        float iv = 1.0f / (sqrtf(s) + EPSV);
        if (lane == 0) inv[row] = iv;
        acc4.x += v.x * iv; acc4.y += v.y * iv; acc4.z += v.z * iv; acc4.w += v.w * iv;
    }
    *reinterpret_cast<float4*>(&cs[wave][lane * 4]) = acc4;
    __syncthreads();
    part[blockIdx.x * 256 + t] = cs[0][t] + cs[1][t] + cs[2][t] + cs[3][t];
}

// ---------------- K3: reduce partials -> colmean; center; write fp8 (x16); sq_norms ----------------
__global__ void k3_center(const float* __restrict__ in, const float* __restrict__ inv,
                          const float* __restrict__ part,
                          unsigned char* __restrict__ cf8, float* __restrict__ sqn) {
    int t = threadIdx.x, lane = t & 63, wave = t >> 6;
    int r0 = blockIdx.x * 32;
    __shared__ float cm[256];
    float m = 0.f;
    #pragma unroll 8
    for (int b = 0; b < 256; ++b) m += part[b * 256 + t];
    cm[t] = m * (1.0f / NROWS);
    __syncthreads();
    float4 m4 = *reinterpret_cast<const float4*>(&cm[lane * 4]);
    #pragma unroll
    for (int rr = 0; rr < 8; ++rr) {
        int row = r0 + wave * 8 + rr;
        float iv = inv[row];
        float4 v = *reinterpret_cast<const float4*>(&in[row * DCOLS + lane * 4]);
        float4 cv = {v.x * iv - m4.x, v.y * iv - m4.y, v.z * iv - m4.z, v.w * iv - m4.w};
        int pk = __builtin_amdgcn_cvt_pk_fp8_f32(cv.x * FP8_SCALE, cv.y * FP8_SCALE, 0, false);
        pk = __builtin_amdgcn_cvt_pk_fp8_f32(cv.z * FP8_SCALE, cv.w * FP8_SCALE, pk, true);
        *reinterpret_cast<int*>(&cf8[row * DCOLS + lane * 4]) = pk;
        float s = cv.x * cv.x + cv.y * cv.y + cv.z * cv.z + cv.w * cv.w;
        #pragma unroll
        for (int o = 1; o < 64; o <<= 1) s += __shfl_xor(s, o);
        if (lane == 0) sqn[row] = s;
    }
}

// ---------------- K4: 128x128 tile, 8 waves (64x32), fp8, DOUBLE-buffer BK=64 ----------------
// LDS 2x(8KB A + 8KB B) = 32KB -> 4 blocks/CU AND stage-ahead pipelining.
// Swizzle: LDS[row][chunk h] = G[row][h ^ ((row>>1)&3)] (16B chunks of 64B row),
// applied on the GLOBAL source; read XORs 8B-granule: g ^= row&6 -> ~2-way (free).
__global__ __launch_bounds__(512, 4) void k4_dist(const unsigned char* __restrict__ cf8,
                                                  const float* __restrict__ sqn,
                                                  float* __restrict__ partial) {
    __shared__ unsigned char As[2][128 * 64];   // 2 x 8KB
    __shared__ unsigned char Bs[2][128 * 64];
    __shared__ float sqA[128], sqB[128];
    __shared__ float red8[8];

    int bid = blockIdx.x;
    int idx = (bid & 7) * (NTILES / 8) + (bid >> 3);   // XCD swizzle, 2080%8==0
    int q = (int)((sqrtf(8.0f * (float)idx + 1.0f) - 1.0f) * 0.5f);
    while ((q + 1) * (q + 2) / 2 <= idx) ++q;
    while (q * (q + 1) / 2 > idx) --q;
    int p = idx - q * (q + 1) / 2;

    int brow = p * 128, bcol = q * 128;
    int t = threadIdx.x, lane = t & 63, wave = t >> 6;
    int wr = wave >> 2, wc = wave & 3;   // 2x4 grid: 64x32 output per wave

    // staging: wave stages rows Rw..Rw+15 (16 rows x 64B = 1KB = one async16).
    // lane l -> row Rw+(l>>2), LDS chunk l&3; source chunk (l&3)^((l>>3)&3).
    int Rw = wave * 16;
    int laneOff = ((lane >> 2) * DCOLS) + ((((lane & 3) ^ ((lane >> 3) & 3))) << 4);
    const char* Ab = (const char*)cf8 + (size_t)(brow + Rw) * DCOLS + laneOff;
    const char* Bb = (const char*)cf8 + (size_t)(bcol + Rw) * DCOLS + laneOff;

    if (t < 128) sqA[t] = sqn[brow + t];
    else if (t < 256) sqB[t - 128] = sqn[bcol + t - 128];

    f32x4 acc[4][2] = {};

    // prologue: stage slice 0 into buffer 0
    async16(&As[0][Rw * 64], Ab);
    async16(&Bs[0][Rw * 64], Bb);
    __syncthreads();

    #pragma unroll
    for (int s = 0; s < 4; ++s) {
        if (s < 3) {   // stage-ahead: issue next slice into other buffer NOW,
                       // latency hides under this slice's compute
            async16(&As[(s + 1) & 1][Rw * 64], Ab + (s + 1) * 64);
            async16(&Bs[(s + 1) & 1][Rw * 64], Bb + (s + 1) * 64);
        }
        const unsigned char* Ar = As[s & 1];
        const unsigned char* Br = Bs[s & 1];
        #pragma unroll
        for (int kk = 0; kk < 2; ++kk) {
            long long af[4], bf[2];
            int g = kk * 4 + (lane >> 4);          // 8B-granule index in 64B row
            #pragma unroll
            for (int m = 0; m < 4; ++m) {
                int row = wr * 64 + m * 16 + (lane & 15);
                int off = row * 64 + ((g ^ (row & 6)) << 3);
                af[m] = *reinterpret_cast<const long long*>(Ar + off);
            }
            #pragma unroll
            for (int n = 0; n < 2; ++n) {
                int row = wc * 32 + n * 16 + (lane & 15);
                int off = row * 64 + ((g ^ (row & 6)) << 3);
                bf[n] = *reinterpret_cast<const long long*>(Br + off);
            }
            #pragma unroll
            for (int m = 0; m < 4; ++m)
                #pragma unroll
                for (int n = 0; n < 2; ++n)
                    acc[m][n] = __builtin_amdgcn_mfma_f32_16x16x32_fp8_fp8(af[m], bf[n], acc[m][n], 0, 0, 0);
        }
        __syncthreads();   // drains vmcnt: next slice landed; current buf free for s+2
    }

    // epilogue: sq_dist = sqn_i + sqn_j - (2/256)*acc; accumulate sqrt
    float local = 0.0f;
    int r4 = (lane >> 4) * 4;
    int cn = lane & 15;
    #pragma unroll
    for (int n = 0; n < 2; ++n) {
        float sj = sqB[wc * 32 + n * 16 + cn];
        #pragma unroll
        for (int m = 0; m < 4; ++m) {
            int i0 = wr * 64 + m * 16 + r4;
            #pragma unroll
            for (int r = 0; r < 4; ++r) {
                float sq = sqA[i0 + r] + sj - GRAM_FIX * acc[m][n][r];
                local += (sq > 0.0f) ? sqrtf(sq) : 0.0f;
            }
        }
    }
    #pragma unroll
    for (int o = 1; o < 64; o <<= 1) local += __shfl_xor(local, o);
    if (lane == 0) red8[wave] = local;
    __syncthreads();
    if (t == 0) {
        float w = (p == q) ? 1.0f : 2.0f;
        float s8 = 0.f;
        #pragma unroll
        for (int i = 0; i < 8; ++i) s8 += red8[i];
        partial[idx] = w * s8;
    }
}

// ---------------- K5: final scalar ----------------
__global__ void k5_final(const float* __restrict__ sqn, const float* __restrict__ partial,
                         float* __restrict__ out) {
    int t = threadIdx.x;
    int lane = t & 63, wave = t >> 6;
    float s = 0.0f;
    for (int r = t; r < NROWS; r += 1024) s += sqn[r];
    double ds = 0.0;
    for (int r = t; r < NTILES; r += 1024) ds += (double)partial[r];
    #pragma unroll
    for (int o = 1; o < 64; o <<= 1) { s += __shfl_xor(s, o); ds += __shfl_xor(ds, o); }
    __shared__ float redf[16];
    __shared__ double redd[16];
    if (lane == 0) { redf[wave] = s; redd[wave] = ds; }
    __syncthreads();
    if (t == 0) {
        float sumsq = 0.f; double sd = 0.0;
        #pragma unroll
        for (int i = 0; i < 16; ++i) { sumsq += redf[i]; sd += redd[i]; }
        double md = sd / ((double)NROWS * (double)NROWS);
        out[0] = (float)DCOLS / sumsq + (float)log(md);
    }
}

extern "C" void kernel_launch(void* const* d_in, const int* in_sizes, int n_in,
                              void* d_out, int out_size, void* d_ws, size_t ws_size,
                              hipStream_t stream) {
    const float* emb = (const float*)d_in[0];
    float* out = (float*)d_out;
    char* ws = (char*)d_ws;

    float*  inv     = (float*)ws;                    // 8192 f32
    float*  sqn     = (float*)(ws + 36864);          // 8192 f32
    float*  partial = (float*)(ws + 69632);          // 2080 f32
    float*  part    = (float*)(ws + 81920);          // 256*256 f32 = 256KB
    unsigned char* cf8 = (unsigned char*)(ws + 81920 + 262144); // 2 MB fp8

    k12_fused <<<NROWS / 32, 256, 0, stream>>>(emb, inv, part);
    k3_center <<<NROWS / 32, 256, 0, stream>>>(emb, inv, part, cf8, sqn);
    k4_dist   <<<NTILES, 512, 0, stream>>>(cf8, sqn, partial);
    k5_final  <<<1, 1024, 0, stream>>>(sqn, partial, out);
}

// Round 12
// 57.479 us; speedup vs baseline: 1.2125x; 1.0473x over previous
//
#include <hip/hip_runtime.h>
#include <hip/hip_bf16.h>

#define NROWS 8192
#define DCOLS 256
#define NTILES 2080   // 64*65/2 upper-triangle 128x128 tiles
constexpr float EPSV = 1e-6f;
constexpr float FP8_SCALE = 16.0f;          // c stored as fp8(16*c)
constexpr float GRAM_FIX = 2.0f / (FP8_SCALE * FP8_SCALE);

typedef __attribute__((ext_vector_type(4))) float f32x4;
typedef __attribute__((ext_vector_type(2))) long long ll2;

__device__ __forceinline__ void async16(void* lds, const void* g) {
    __builtin_amdgcn_global_load_lds(
        (const __attribute__((address_space(1))) void*)g,
        (__attribute__((address_space(3))) void*)lds, 16, 0, 0);
}

#define SBAR() do { __builtin_amdgcn_sched_barrier(0); __builtin_amdgcn_s_barrier(); \
                    __builtin_amdgcn_sched_barrier(0); } while (0)
#define VMWAIT(N) asm volatile("s_waitcnt vmcnt(" #N ")" ::: "memory")

// ---------------- K12: row norms + per-block colsum partials ----------------
__global__ void k12_fused(const float* __restrict__ in, float* __restrict__ inv,
                          float* __restrict__ part) {
    int t = threadIdx.x, lane = t & 63, wave = t >> 6;
    int r0 = blockIdx.x * 32;
    __shared__ float cs[4][256];
    float4 acc4 = {0.f, 0.f, 0.f, 0.f};
    #pragma unroll
    for (int rr = 0; rr < 8; ++rr) {
        int row = r0 + wave * 8 + rr;
        float4 v = *reinterpret_cast<const float4*>(&in[row * DCOLS + lane * 4]);
        float s = v.x * v.x + v.y * v.y + v.z * v.z + v.w * v.w;
        #pragma unroll
        for (int o = 1; o < 64; o <<= 1) s += __shfl_xor(s, o);
        float iv = 1.0f / (sqrtf(s) + EPSV);
        if (lane == 0) inv[row] = iv;
        acc4.x += v.x * iv; acc4.y += v.y * iv; acc4.z += v.z * iv; acc4.w += v.w * iv;
    }
    *reinterpret_cast<float4*>(&cs[wave][lane * 4]) = acc4;
    __syncthreads();
    part[blockIdx.x * 256 + t] = cs[0][t] + cs[1][t] + cs[2][t] + cs[3][t];
}

// ---------------- K3: colmean; center; write PACKED fp8 (x16); sq_norms ----------------
// Packed row layout (256B/row): byte(k) = (k>>6)*64 + (((k&31)>>3)<<4) + ((k>>5)&1)*8 + (k&7)
// so a 16B granule [slice*64 + y*16 .. +16) = { k in [s*64+y*8, +8) } (lo 8B, kk=2s)
//                                           ∪ { k in [s*64+32+y*8, +8) } (hi 8B, kk=2s+1).
__global__ void k3_center(const float* __restrict__ in, const float* __restrict__ inv,
                          const float* __restrict__ part,
                          unsigned char* __restrict__ cf8, float* __restrict__ sqn) {
    int t = threadIdx.x, lane = t & 63, wave = t >> 6;
    int r0 = blockIdx.x * 32;
    __shared__ float cm[256];
    float m = 0.f;
    #pragma unroll 8
    for (int b = 0; b < 256; ++b) m += part[b * 256 + t];
    cm[t] = m * (1.0f / NROWS);
    __syncthreads();
    float4 m4 = *reinterpret_cast<const float4*>(&cm[lane * 4]);
    int k0 = lane * 4;
    int s4 = k0 >> 6, kp = k0 & 63, h = kp >> 5, kpp = kp & 31;
    int pos = s4 * 64 + ((kpp >> 3) << 4) + h * 8 + (kpp & 7);   // per-lane constant
    #pragma unroll
    for (int rr = 0; rr < 8; ++rr) {
        int row = r0 + wave * 8 + rr;
        float iv = inv[row];
        float4 v = *reinterpret_cast<const float4*>(&in[row * DCOLS + k0]);
        float4 cv = {v.x * iv - m4.x, v.y * iv - m4.y, v.z * iv - m4.z, v.w * iv - m4.w};
        int pk = __builtin_amdgcn_cvt_pk_fp8_f32(cv.x * FP8_SCALE, cv.y * FP8_SCALE, 0, false);
        pk = __builtin_amdgcn_cvt_pk_fp8_f32(cv.z * FP8_SCALE, cv.w * FP8_SCALE, pk, true);
        *reinterpret_cast<int*>(&cf8[row * DCOLS + pos]) = pk;
        float s = cv.x * cv.x + cv.y * cv.y + cv.z * cv.z + cv.w * cv.w;
        #pragma unroll
        for (int o = 1; o < 64; o <<= 1) s += __shfl_xor(s, o);
        if (lane == 0) sqn[row] = s;
    }
}

// ---------------- K4: 128x128 fp8 tile, 8 waves (64x32), counted-vmcnt dbuf ----------------
__device__ __forceinline__ void compute_slice(const unsigned char* Ar, const unsigned char* Br,
                                              int aBase, int bBase, f32x4 acc[4][2]) {
    ll2 a[4], b[2];
    #pragma unroll
    for (int m = 0; m < 4; ++m)
        a[m] = *reinterpret_cast<const ll2*>(Ar + aBase + m * 1024);
    #pragma unroll
    for (int n = 0; n < 2; ++n)
        b[n] = *reinterpret_cast<const ll2*>(Br + bBase + n * 1024);
    #pragma unroll
    for (int m = 0; m < 4; ++m)
        #pragma unroll
        for (int n = 0; n < 2; ++n) {
            acc[m][n] = __builtin_amdgcn_mfma_f32_16x16x32_fp8_fp8(a[m].x, b[n].x, acc[m][n], 0, 0, 0);
            acc[m][n] = __builtin_amdgcn_mfma_f32_16x16x32_fp8_fp8(a[m].y, b[n].y, acc[m][n], 0, 0, 0);
        }
}

__global__ __launch_bounds__(512, 4) void k4_dist(const unsigned char* __restrict__ cf8,
                                                  const float* __restrict__ sqn,
                                                  float* __restrict__ partial) {
    __shared__ unsigned char As[2][128 * 64];   // 2 x 8KB
    __shared__ unsigned char Bs[2][128 * 64];
    __shared__ float sqA[128], sqB[128];
    __shared__ float red8[8];

    int bid = blockIdx.x;
    int idx = (bid & 7) * (NTILES / 8) + (bid >> 3);
    int q = (int)((sqrtf(8.0f * (float)idx + 1.0f) - 1.0f) * 0.5f);
    while ((q + 1) * (q + 2) / 2 <= idx) ++q;
    while (q * (q + 1) / 2 > idx) --q;
    int p = idx - q * (q + 1) / 2;

    int brow = p * 128, bcol = q * 128;
    int t = threadIdx.x, lane = t & 63, wave = t >> 6;
    int wr = wave >> 2, wc = wave & 3;   // 2x4 grid: 64x32 per wave

    // staging: wave stages rows Rw..Rw+15 (1 async16 each for A and B per slice).
    // lane l -> LDS row Rw+(l>>2), chunk l&3; source chunk (l&3)^((l>>3)&3).
    int Rw = wave * 16;
    int laneOff = ((lane >> 2) * DCOLS) + ((((lane & 3) ^ ((lane >> 3) & 3))) << 4);
    const char* Asrc = (const char*)cf8 + (size_t)(brow + Rw) * DCOLS + laneOff;
    const char* Bsrc = (const char*)cf8 + (size_t)(bcol + Rw) * DCOLS + laneOff;

    // read addressing (per-lane constants + immediate offsets)
    int xc = (lane >> 4) ^ (((lane & 15) >> 1) & 3);
    int aBase = (wr * 64 + (lane & 15)) * 64 + xc * 16;
    int bBase = (wc * 32 + (lane & 15)) * 64 + xc * 16;

    if (t < 128) sqA[t] = sqn[brow + t];
    else if (t < 256) sqB[t - 128] = sqn[bcol + t - 128];

    f32x4 acc[4][2] = {};

    // prologue: stage slices 0,1
    async16(&As[0][Rw * 64], Asrc);           async16(&Bs[0][Rw * 64], Bsrc);
    async16(&As[1][Rw * 64], Asrc + 64);      async16(&Bs[1][Rw * 64], Bsrc + 64);
    __syncthreads();                           // drains vmcnt+lgkm: slices 0,1 + sqn ready

    compute_slice(As[0], Bs[0], aBase, bBase, acc);          // s=0
    SBAR();                                                   // all done reading b0
    async16(&As[0][Rw * 64], Asrc + 128);     async16(&Bs[0][Rw * 64], Bsrc + 128);  // stage2
    compute_slice(As[1], Bs[1], aBase, bBase, acc);          // s=1 (hides stage2)
    SBAR();                                                   // all done reading b1
    async16(&As[1][Rw * 64], Asrc + 192);     async16(&Bs[1][Rw * 64], Bsrc + 192);  // stage3
    VMWAIT(2);                                                // my stage2 landed
    SBAR();                                                   // everyone's stage2 landed
    compute_slice(As[0], Bs[0], aBase, bBase, acc);          // s=2 (hides stage3)
    VMWAIT(0);                                                // my stage3 landed
    SBAR();                                                   // everyone's stage3 landed
    compute_slice(As[1], Bs[1], aBase, bBase, acc);          // s=3

    // epilogue: sq_dist = sqn_i + sqn_j - (2/256)*acc; accumulate sqrt
    float local = 0.0f;
    int r4 = (lane >> 4) * 4;
    int cn = lane & 15;
    #pragma unroll
    for (int n = 0; n < 2; ++n) {
        float sj = sqB[wc * 32 + n * 16 + cn];
        #pragma unroll
        for (int m = 0; m < 4; ++m) {
            int i0 = wr * 64 + m * 16 + r4;
            #pragma unroll
            for (int r = 0; r < 4; ++r) {
                float sq = sqA[i0 + r] + sj - GRAM_FIX * acc[m][n][r];
                local += (sq > 0.0f) ? sqrtf(sq) : 0.0f;
            }
        }
    }
    #pragma unroll
    for (int o = 1; o < 64; o <<= 1) local += __shfl_xor(local, o);
    if (lane == 0) red8[wave] = local;
    __syncthreads();
    if (t == 0) {
        float w = (p == q) ? 1.0f : 2.0f;
        float s8 = 0.f;
        #pragma unroll
        for (int i = 0; i < 8; ++i) s8 += red8[i];
        partial[idx] = w * s8;
    }
}

// ---------------- K5: final scalar ----------------
__global__ void k5_final(const float* __restrict__ sqn, const float* __restrict__ partial,
                         float* __restrict__ out) {
    int t = threadIdx.x;
    int lane = t & 63, wave = t >> 6;
    float s = 0.0f;
    for (int r = t; r < NROWS; r += 1024) s += sqn[r];
    double ds = 0.0;
    for (int r = t; r < NTILES; r += 1024) ds += (double)partial[r];
    #pragma unroll
    for (int o = 1; o < 64; o <<= 1) { s += __shfl_xor(s, o); ds += __shfl_xor(ds, o); }
    __shared__ float redf[16];
    __shared__ double redd[16];
    if (lane == 0) { redf[wave] = s; redd[wave] = ds; }
    __syncthreads();
    if (t == 0) {
        float sumsq = 0.f; double sd = 0.0;
        #pragma unroll
        for (int i = 0; i < 16; ++i) { sumsq += redf[i]; sd += redd[i]; }
        double md = sd / ((double)NROWS * (double)NROWS);
        out[0] = (float)DCOLS / sumsq + (float)log(md);
    }
}

extern "C" void kernel_launch(void* const* d_in, const int* in_sizes, int n_in,
                              void* d_out, int out_size, void* d_ws, size_t ws_size,
                              hipStream_t stream) {
    const float* emb = (const float*)d_in[0];
    float* out = (float*)d_out;
    char* ws = (char*)d_ws;

    float*  inv     = (float*)ws;                    // 8192 f32
    float*  sqn     = (float*)(ws + 36864);          // 8192 f32
    float*  partial = (float*)(ws + 69632);          // 2080 f32
    float*  part    = (float*)(ws + 81920);          // 256*256 f32 = 256KB
    unsigned char* cf8 = (unsigned char*)(ws + 81920 + 262144); // 2 MB packed fp8

    k12_fused <<<NROWS / 32, 256, 0, stream>>>(emb, inv, part);
    k3_center <<<NROWS / 32, 256, 0, stream>>>(emb, inv, part, cf8, sqn);
    k4_dist   <<<NTILES, 512, 0, stream>>>(cf8, sqn, partial);
    k5_final  <<<1, 1024, 0, stream>>>(sqn, partial, out);
}